// Round 1
// baseline (300.756 us; speedup 1.0000x reference)
//
#include <hip/hip_runtime.h>

#define NPTS 16384
#define NB   8
#define NM   2048
#define NC   128
#define EPSF 1e-8f

// lexicographic (d, idx) "better" — matches jax.lax.top_k tie-break (lower idx first)
__device__ __forceinline__ bool better(float d, int i, float dr, int ir) {
    return (d < dr) || ((d == dr) && (i < ir));
}

__device__ __forceinline__ void insert3(float d, int j,
                                        float& d0, int& i0,
                                        float& d1, int& i1,
                                        float& d2, int& i2) {
    if (better(d, j, d2, i2)) {
        if (better(d, j, d1, i1)) {
            if (better(d, j, d0, i0)) {
                d2 = d1; i2 = i1; d1 = d0; i1 = i0; d0 = d; i0 = j;
            } else {
                d2 = d1; i2 = i1; d1 = d; i1 = j;
            }
        } else {
            d2 = d; i2 = j;
        }
    }
}

// (B, C, M) -> (B, M, C) tiled transpose, +1 pad kills bank conflicts
__global__ __launch_bounds__(256) void transpose_feats(const float* __restrict__ in,
                                                       float* __restrict__ out) {
    __shared__ float tile[32][33];
    const int b  = blockIdx.z;
    const int j0 = blockIdx.x * 32;   // M dim
    const int c0 = blockIdx.y * 32;   // C dim
    const int tx = threadIdx.x;       // 32
    const int ty = threadIdx.y;       // 8
#pragma unroll
    for (int i = ty; i < 32; i += 8)
        tile[i][tx] = in[(size_t)b * NC * NM + (size_t)(c0 + i) * NM + (j0 + tx)];
    __syncthreads();
#pragma unroll
    for (int i = ty; i < 32; i += 8)
        out[(size_t)b * NM * NC + (size_t)(j0 + i) * NC + (c0 + tx)] = tile[tx][i];
}

// one wave (64 lanes) per query point: 3-NN over 2048 points, then interpolate 128 channels
__global__ __launch_bounds__(256) void nn_interp(const float* __restrict__ unknown,
                                                 const float* __restrict__ known,
                                                 const int*   __restrict__ binds,
                                                 const float* __restrict__ feats,   // (B,C,M)
                                                 const float* __restrict__ featsT,  // (B,M,C)
                                                 float* __restrict__ out,
                                                 int useT) {
    const int wave = threadIdx.x >> 6;
    const int lane = threadIdx.x & 63;
    const int p    = blockIdx.x * 4 + wave;   // grid = NPTS/4 blocks of 4 waves

    const int b = binds[p];
    const float ux = unknown[p * 3 + 0];
    const float uy = unknown[p * 3 + 1];
    const float uz = unknown[p * 3 + 2];

    const float* kb = known + (size_t)b * NM * 3;

    float d0 = __builtin_inff(), d1 = __builtin_inff(), d2 = __builtin_inff();
    int   i0 = NM, i1 = NM, i2 = NM;

#pragma unroll 4
    for (int it = 0; it < NM / 64; ++it) {
        const int j = it * 64 + lane;
        const float kx = kb[j * 3 + 0];
        const float ky = kb[j * 3 + 1];
        const float kz = kb[j * 3 + 2];
        // strict round-to-nearest, numpy association ((dx2+dy2)+dz2); no FMA contraction
        const float dx = __fsub_rn(ux, kx);
        const float dy = __fsub_rn(uy, ky);
        const float dz = __fsub_rn(uz, kz);
        const float d  = __fadd_rn(__fadd_rn(__fmul_rn(dx, dx), __fmul_rn(dy, dy)),
                                   __fmul_rn(dz, dz));
        insert3(d, j, d0, i0, d1, i1, d2, i2);
    }

    // shfl_down tree reduce (disjoint sublists at every live step — no duplicate entries),
    // result valid at lane 0, then broadcast.
#pragma unroll
    for (int off = 32; off >= 1; off >>= 1) {
        const float e0 = __shfl_down(d0, off);
        const float e1 = __shfl_down(d1, off);
        const float e2 = __shfl_down(d2, off);
        const int   j0 = __shfl_down(i0, off);
        const int   j1 = __shfl_down(i1, off);
        const int   j2 = __shfl_down(i2, off);
        insert3(e0, j0, d0, i0, d1, i1, d2, i2);
        insert3(e1, j1, d0, i0, d1, i1, d2, i2);
        insert3(e2, j2, d0, i0, d1, i1, d2, i2);
    }
    d0 = __shfl(d0, 0); d1 = __shfl(d1, 0); d2 = __shfl(d2, 0);
    i0 = __shfl(i0, 0); i1 = __shfl(i1, 0); i2 = __shfl(i2, 0);

    // weights: w_k = (1/(sqrt(d_k)+eps)) / sum
    const float t0 = 1.0f / (sqrtf(d0) + EPSF);
    const float t1 = 1.0f / (sqrtf(d1) + EPSF);
    const float t2 = 1.0f / (sqrtf(d2) + EPSF);
    const float s  = t0 + t1 + t2;
    const float w0 = t0 / s, w1 = t1 / s, w2 = t2 / s;

    if (useT) {
        const float* ft  = featsT + (size_t)b * NM * NC;
        const float* f0p = ft + (size_t)i0 * NC;
        const float* f1p = ft + (size_t)i1 * NC;
        const float* f2p = ft + (size_t)i2 * NC;
#pragma unroll
        for (int c = lane; c < NC; c += 64) {
            out[(size_t)p * NC + c] = w0 * f0p[c] + w1 * f1p[c] + w2 * f2p[c];
        }
    } else {
        const float* fb = feats + (size_t)b * NC * NM;
#pragma unroll
        for (int c = lane; c < NC; c += 64) {
            const float* fc = fb + (size_t)c * NM;
            out[(size_t)p * NC + c] = w0 * fc[i0] + w1 * fc[i1] + w2 * fc[i2];
        }
    }
}

extern "C" void kernel_launch(void* const* d_in, const int* in_sizes, int n_in,
                              void* d_out, int out_size, void* d_ws, size_t ws_size,
                              hipStream_t stream) {
    const float* unknown = (const float*)d_in[0];   // (n, 3)
    const float* known   = (const float*)d_in[1];   // (B, m, 3)
    const int*   binds   = (const int*)d_in[2];     // (n,)
    const float* feats   = (const float*)d_in[3];   // (B, C, m)
    float*       out     = (float*)d_out;           // (n, C, 1)

    const size_t featsBytes = (size_t)NB * NC * NM * sizeof(float);
    const int useT = (ws_size >= featsBytes) ? 1 : 0;
    float* featsT = (float*)d_ws;

    if (useT) {
        dim3 tb(32, 8, 1);
        dim3 tg(NM / 32, NC / 32, NB);
        transpose_feats<<<tg, tb, 0, stream>>>(feats, featsT);
    }
    nn_interp<<<NPTS / 4, 256, 0, stream>>>(unknown, known, binds, feats, featsT, out, useT);
}